// Round 1
// baseline (19070.131 us; speedup 1.0000x reference)
//
#include <hip/hip_runtime.h>
#include <hip/hip_bf16.h>
#include <math.h>

#define BB     64
#define TENC   100
#define TDEC   50
#define LDIM   512
#define EE     512
#define HDIM   512
#define FIVEL  2560
#define RSTEPS 8
#define VOUT   30000

__device__ __forceinline__ float sigmoidf_(float x) { return 1.0f / (1.0f + __expf(-x)); }

// ---------------------------------------------------------------------------
// Generic fp32 GEMM: C[m][n] = sum_k A[m][k]*Bw[k][n] + bias[n]
// If tok != nullptr, A row m is gathered: t = m/BB, b = m%BB, row = tok[b*tokT+t]
// (A is then the embedding table with row stride K).
// Tile 64x64, BK=16, 256 threads, 4x4 per thread. M must be multiple of 64.
// N may be ragged (guarded). ldc = row stride of C.
// ---------------------------------------------------------------------------
__global__ __launch_bounds__(256)
void gemm_f32(const float* __restrict__ A, const int* __restrict__ tok, int tokT,
              const float* __restrict__ Bw, const float* __restrict__ bias,
              float* __restrict__ C, int M, int N, int K, long ldc)
{
    __shared__ float As[16][64];   // [k][m]
    __shared__ float Bs[16][64];   // [k][n]
    const int tid = threadIdx.x;
    const int m0 = blockIdx.y * 64, n0 = blockIdx.x * 64;
    const int tm = tid >> 4, tn = tid & 15;

    float acc[4][4] = {};

    for (int k0 = 0; k0 < K; k0 += 16) {
        // A tile: 64 rows x 16 k. 256 threads, each one float4.
        {
            int r  = tid >> 2;
            int kk = (tid & 3) * 4;
            int m  = m0 + r;
            const float* arow;
            if (tok) {
                int t = m / BB, b = m % BB;
                arow = A + (long)tok[b * tokT + t] * K;
            } else {
                arow = A + (long)m * K;
            }
            float4 v = *(const float4*)(arow + k0 + kk);
            As[kk + 0][r] = v.x; As[kk + 1][r] = v.y;
            As[kk + 2][r] = v.z; As[kk + 3][r] = v.w;
        }
        // B tile: 16 k x 64 n
        {
            int kk = tid >> 4;
            int n  = n0 + (tid & 15) * 4;
            const float* brow = Bw + (long)(k0 + kk) * N;
            float4 v;
            if (n + 3 < N) {
                v = *(const float4*)(brow + n);
            } else {
                v.x = (n + 0 < N) ? brow[n + 0] : 0.f;
                v.y = (n + 1 < N) ? brow[n + 1] : 0.f;
                v.z = (n + 2 < N) ? brow[n + 2] : 0.f;
                v.w = (n + 3 < N) ? brow[n + 3] : 0.f;
            }
            *(float4*)&Bs[kk][(tid & 15) * 4] = v;
        }
        __syncthreads();
        #pragma unroll
        for (int k = 0; k < 16; ++k) {
            float4 a = *(const float4*)&As[k][tm * 4];
            float4 b = *(const float4*)&Bs[k][tn * 4];
            float av[4] = {a.x, a.y, a.z, a.w};
            float bv[4] = {b.x, b.y, b.z, b.w};
            #pragma unroll
            for (int i = 0; i < 4; ++i)
                #pragma unroll
                for (int j = 0; j < 4; ++j)
                    acc[i][j] += av[i] * bv[j];
        }
        __syncthreads();
    }

    #pragma unroll
    for (int i = 0; i < 4; ++i) {
        int m = m0 + tm * 4 + i;
        float* crow = C + (long)m * ldc;
        int n = n0 + tn * 4;
        if (n + 3 < N) {
            float4 bv = bias ? *(const float4*)(bias + n) : make_float4(0.f, 0.f, 0.f, 0.f);
            float4 v  = make_float4(acc[i][0] + bv.x, acc[i][1] + bv.y,
                                    acc[i][2] + bv.z, acc[i][3] + bv.w);
            *(float4*)(crow + n) = v;
        } else {
            #pragma unroll
            for (int j = 0; j < 4; ++j)
                if (n + j < N) crow[n + j] = acc[i][j] + (bias ? bias[n + j] : 0.f);
        }
    }
}

// ---------------------------------------------------------------------------
// Small projection: out[b][n] = sum_k h[b][k]*W[k][n] + bias[n]
// B=64, N=512, K=512. grid (32,4), 256 threads.
// ---------------------------------------------------------------------------
__global__ __launch_bounds__(256)
void proj_h(const float* __restrict__ h, const float* __restrict__ W,
            const float* __restrict__ bias, float* __restrict__ out)
{
    __shared__ float hs[16][516];
    const int b0 = blockIdx.y * 16, n0 = blockIdx.x * 16;
    const int tid = threadIdx.x;
    {
        int r = tid >> 4, c4 = (tid & 15) * 4;
        #pragma unroll
        for (int j = 0; j < 8; ++j)
            *(float4*)&hs[r][c4 + 64 * j] = *(const float4*)&h[(b0 + r) * LDIM + c4 + 64 * j];
    }
    __syncthreads();
    const int bi = tid >> 4, ni = tid & 15;
    const int n = n0 + ni;
    float acc = 0.f;
    #pragma unroll 4
    for (int k = 0; k < LDIM; ++k) acc += hs[bi][k] * W[(long)k * HDIM + n];
    out[(b0 + bi) * HDIM + n] = acc + bias[n];
}

// ---------------------------------------------------------------------------
// Fused LSTM (maxout) step.
// s[b][n + j*L] = bh[n+jL] (+ ba[n+jL]) (+ pre[b][n+jL])
//              + sum_k h[b][k]*Wh[k][n+jL] (+ sum_k att[b][k]*Wa[k][n+jL])
// gates -> h_out, c_out (and optional h_store copy).
// grid (LDIM/16=32, BB/16=4), 256 threads.
// ---------------------------------------------------------------------------
__global__ __launch_bounds__(256)
void lstm_step(const float* __restrict__ pre,
               const float* __restrict__ h_in, const float* __restrict__ c_in,
               const float* __restrict__ Wh, const float* __restrict__ bh,
               const float* __restrict__ att,
               const float* __restrict__ Wa, const float* __restrict__ ba,
               float* __restrict__ h_out, float* __restrict__ c_out,
               float* __restrict__ h_store)
{
    __shared__ float hs[16][516];
    __shared__ float as_[16][516];
    const int b0 = blockIdx.y * 16, n0 = blockIdx.x * 16;
    const int tid = threadIdx.x;
    {
        int r = tid >> 4, c4 = (tid & 15) * 4;
        #pragma unroll
        for (int j = 0; j < 8; ++j)
            *(float4*)&hs[r][c4 + 64 * j] = *(const float4*)&h_in[(b0 + r) * LDIM + c4 + 64 * j];
        if (att) {
            #pragma unroll
            for (int j = 0; j < 8; ++j)
                *(float4*)&as_[r][c4 + 64 * j] = *(const float4*)&att[(b0 + r) * LDIM + c4 + 64 * j];
        }
    }
    __syncthreads();
    const int bi = tid >> 4, ni = tid & 15;
    const int b = b0 + bi, n = n0 + ni;

    float s[5];
    #pragma unroll
    for (int j = 0; j < 5; ++j) s[j] = bh[n + j * LDIM];
    if (ba) {
        #pragma unroll
        for (int j = 0; j < 5; ++j) s[j] += ba[n + j * LDIM];
    }
    if (pre) {
        #pragma unroll
        for (int j = 0; j < 5; ++j) s[j] += pre[(long)b * FIVEL + n + j * LDIM];
    }
    #pragma unroll 4
    for (int k = 0; k < LDIM; ++k) {
        float hk = hs[bi][k];
        const float* w = Wh + (long)k * FIVEL + n;
        #pragma unroll
        for (int j = 0; j < 5; ++j) s[j] += hk * w[j * LDIM];
    }
    if (att) {
        #pragma unroll 4
        for (int k = 0; k < LDIM; ++k) {
            float ak = as_[bi][k];
            const float* w = Wa + (long)k * FIVEL + n;
            #pragma unroll
            for (int j = 0; j < 5; ++j) s[j] += ak * w[j * LDIM];
        }
    }
    float ig = sigmoidf_(s[0]);
    float fg = sigmoidf_(s[1]);
    float og = sigmoidf_(s[2]);
    float tt = fmaxf(s[3], s[4]);
    float c2 = fg * c_in[(long)b * LDIM + n] + ig * tt;
    float h2 = og * tanhf(c2);
    h_out[(long)b * LDIM + n] = h2;
    c_out[(long)b * LDIM + n] = c2;
    if (h_store) h_store[(long)b * LDIM + n] = h2;
}

// ---------------------------------------------------------------------------
// Fused attention: e[a] = sum_h tanh(proj[a][b][h] + hproj[b][h])*Watt[h];
// alpha = softmax(e); att_v[b][l] = sum_a alpha[a]*feats[a][b][l].
// (batt dropped: softmax is shift-invariant.)  One block per b, 256 threads.
// proj/feats laid out [A][B][*].
// ---------------------------------------------------------------------------
__global__ __launch_bounds__(256)
void attend(const float* __restrict__ proj, const float* __restrict__ hproj,
            const float* __restrict__ feats, const float* __restrict__ Watt,
            float* __restrict__ att_v, int A)
{
    __shared__ float hp[512];
    __shared__ float wa[512];
    __shared__ float ealpha[128];
    const int b = blockIdx.x;
    const int tid = threadIdx.x;
    for (int i = tid; i < 512; i += 256) { hp[i] = hproj[b * HDIM + i]; wa[i] = Watt[i]; }
    __syncthreads();
    const int wave = tid >> 6, lane = tid & 63;
    for (int a = wave; a < A; a += 4) {
        const float* pr = proj + ((long)a * BB + b) * HDIM;
        float e = 0.f;
        #pragma unroll
        for (int j = 0; j < 8; ++j) {
            int hcol = lane + 64 * j;
            e += tanhf(pr[hcol] + hp[hcol]) * wa[hcol];
        }
        #pragma unroll
        for (int off = 32; off; off >>= 1) e += __shfl_xor(e, off);
        if (lane == 0) ealpha[a] = e;
    }
    __syncthreads();
    if (wave == 0) {
        float v1 = (lane < A) ? ealpha[lane] : -3.0e38f;
        float v2 = (lane + 64 < A) ? ealpha[lane + 64] : -3.0e38f;
        float m = fmaxf(v1, v2);
        #pragma unroll
        for (int off = 32; off; off >>= 1) m = fmaxf(m, __shfl_xor(m, off));
        float x1 = (lane < A) ? __expf(v1 - m) : 0.f;
        float x2 = (lane + 64 < A) ? __expf(v2 - m) : 0.f;
        float ssum = x1 + x2;
        #pragma unroll
        for (int off = 32; off; off >>= 1) ssum += __shfl_xor(ssum, off);
        float inv = 1.0f / ssum;
        if (lane < A) ealpha[lane] = x1 * inv;
        if (lane + 64 < A) ealpha[lane + 64] = x2 * inv;
    }
    __syncthreads();
    #pragma unroll
    for (int jj = 0; jj < 2; ++jj) {
        int l = tid + jj * 256;
        float acc = 0.f;
        for (int a = 0; a < A; ++a) acc += ealpha[a] * feats[((long)a * BB + b) * LDIM + l];
        att_v[(long)b * LDIM + l] = acc;
    }
}

// ---------------------------------------------------------------------------
// In-place log-softmax of one length-VOUT row per block (online max/sum).
// ---------------------------------------------------------------------------
__global__ __launch_bounds__(256)
void log_softmax_(float* __restrict__ out, long ldc)
{
    const int b = blockIdx.x;
    float* row = out + (long)b * ldc;
    const int tid = threadIdx.x;
    float m = -3.0e38f, s = 0.f;
    for (int i = tid; i < VOUT; i += 256) {
        float x = row[i];
        if (x > m) { s = s * __expf(m - x) + 1.0f; m = x; }
        else       { s += __expf(x - m); }
    }
    #pragma unroll
    for (int off = 32; off; off >>= 1) {
        float mo = __shfl_xor(m, off);
        float so = __shfl_xor(s, off);
        float mn = fmaxf(m, mo);
        s = s * __expf(m - mn) + so * __expf(mo - mn);
        m = mn;
    }
    __shared__ float ms[4], ss[4];
    const int wave = tid >> 6, lane = tid & 63;
    if (lane == 0) { ms[wave] = m; ss[wave] = s; }
    __syncthreads();
    float M2 = fmaxf(fmaxf(ms[0], ms[1]), fmaxf(ms[2], ms[3]));
    float S2 = ss[0] * __expf(ms[0] - M2) + ss[1] * __expf(ms[1] - M2) +
               ss[2] * __expf(ms[2] - M2) + ss[3] * __expf(ms[3] - M2);
    float lse = M2 + __logf(S2);
    for (int i = tid; i < VOUT; i += 256) row[i] -= lse;
}

// ---------------------------------------------------------------------------
extern "C" void kernel_launch(void* const* d_in, const int* in_sizes, int n_in,
                              void* d_out_, int out_size, void* d_ws, size_t ws_size,
                              hipStream_t stream)
{
    const int*   code     = (const int*)  d_in[0];
    const int*   comment  = (const int*)  d_in[1];
    const float* embed    = (const float*)d_in[3];
    const float* enc_Wi   = (const float*)d_in[4];
    const float* enc_bi   = (const float*)d_in[5];
    const float* enc_Wh   = (const float*)d_in[6];
    const float* enc_bh   = (const float*)d_in[7];
    const float* rev_Wh   = (const float*)d_in[8];
    const float* rev_bh   = (const float*)d_in[9];
    const float* rev_Wa   = (const float*)d_in[10];
    const float* rev_ba   = (const float*)d_in[11];
    const float* rev_Wa2a = (const float*)d_in[12];
    const float* rev_ba2a = (const float*)d_in[13];
    const float* rev_Wh2a = (const float*)d_in[14];
    const float* rev_bh2a = (const float*)d_in[15];
    const float* rev_Watt = (const float*)d_in[16];
    const float* dec_Wi   = (const float*)d_in[18];
    const float* dec_bi   = (const float*)d_in[19];
    const float* dec_Wh   = (const float*)d_in[20];
    const float* dec_bh   = (const float*)d_in[21];
    const float* dec_Wa   = (const float*)d_in[22];
    const float* dec_ba   = (const float*)d_in[23];
    const float* dec_Wa2a = (const float*)d_in[24];
    const float* dec_ba2a = (const float*)d_in[25];
    const float* dec_Wh2a = (const float*)d_in[26];
    const float* dec_bh2a = (const float*)d_in[27];
    const float* dec_Watt = (const float*)d_in[28];
    const float* logit_W  = (const float*)d_in[30];
    const float* logit_b  = (const float*)d_in[31];
    float* out = (float*)d_out_;

    // ---- workspace carve-up (floats) ----
    float* ws = (float*)d_ws;
    size_t need = 0;
    float* enc_pre  = ws + need; need += (size_t)TENC * BB * FIVEL;   // 16,384,000
    float* dec_pre  = ws + need; need += (size_t)TDEC * BB * FIVEL;   //  8,192,000
    float* enc_hs   = ws + need; need += (size_t)TENC * BB * LDIM;    //  3,276,800
    float* rev_proj = ws + need; need += (size_t)TENC * BB * HDIM;    //  3,276,800
    float* thought  = ws + need; need += (size_t)RSTEPS * BB * LDIM;  //    262,144
    float* tproj    = ws + need; need += (size_t)RSTEPS * BB * HDIM;  //    262,144
    float* hbuf[4]; float* cbuf[4];
    for (int i = 0; i < 4; ++i) { hbuf[i] = ws + need; need += (size_t)BB * LDIM; }
    for (int i = 0; i < 4; ++i) { cbuf[i] = ws + need; need += (size_t)BB * LDIM; }
    float* hproj = ws + need; need += (size_t)BB * HDIM;
    float* attv  = ws + need; need += (size_t)BB * LDIM;
    if (ws_size < need * sizeof(float)) return;   // insufficient scratch: bail loudly

    const dim3 blk(256);
    const dim3 gLstm(LDIM / 16, BB / 16);   // (32,4)
    const dim3 gProj(HDIM / 16, BB / 16);   // (32,4)

    hipMemsetAsync(hbuf[0], 0, (size_t)BB * LDIM * sizeof(float), stream);
    hipMemsetAsync(cbuf[0], 0, (size_t)BB * LDIM * sizeof(float), stream);

    // ---- hoisted input GEMMs (parallel over all timesteps) ----
    gemm_f32<<<dim3(FIVEL / 64, TENC * BB / 64), blk, 0, stream>>>(
        embed, code, TENC, enc_Wi, enc_bi, enc_pre, TENC * BB, FIVEL, EE, FIVEL);
    gemm_f32<<<dim3(FIVEL / 64, TDEC * BB / 64), blk, 0, stream>>>(
        embed, comment, TDEC, dec_Wi, dec_bi, dec_pre, TDEC * BB, FIVEL, EE, FIVEL);

    // ---- encoder scan ----
    float *hc = hbuf[0], *cc = cbuf[0], *hn = hbuf[1], *cn = cbuf[1];
    for (int t = 0; t < TENC; ++t) {
        lstm_step<<<gLstm, blk, 0, stream>>>(
            enc_pre + (size_t)t * BB * FIVEL, hc, cc, enc_Wh, enc_bh,
            nullptr, nullptr, nullptr, hn, cn, enc_hs + (size_t)t * BB * LDIM);
        float* tp;
        tp = hc; hc = hn; hn = tp;
        tp = cc; cc = cn; cn = tp;
    }
    float* h_enc = hc;
    float* c_enc = cc;

    // ---- review scan (keeps h_enc/c_enc intact for the decoder) ----
    float* rh = h_enc; float* rc = c_enc;
    int tog = 0;
    for (int r = 0; r < RSTEPS; ++r) {
        gemm_f32<<<dim3(HDIM / 64, TENC * BB / 64), blk, 0, stream>>>(
            enc_hs, nullptr, 0, rev_Wa2a + (size_t)r * LDIM * HDIM,
            rev_ba2a + (size_t)r * HDIM, rev_proj, TENC * BB, HDIM, LDIM, HDIM);
        proj_h<<<gProj, blk, 0, stream>>>(
            rh, rev_Wh2a + (size_t)r * LDIM * HDIM, rev_bh2a + (size_t)r * HDIM, hproj);
        attend<<<BB, blk, 0, stream>>>(rev_proj, hproj, enc_hs,
                                       rev_Watt + (size_t)r * HDIM, attv, TENC);
        float* ho = hbuf[2 + tog]; float* co = cbuf[2 + tog];
        lstm_step<<<gLstm, blk, 0, stream>>>(
            nullptr, rh, rc, rev_Wh + (size_t)r * LDIM * FIVEL, rev_bh + (size_t)r * FIVEL,
            attv, rev_Wa + (size_t)r * LDIM * FIVEL, rev_ba + (size_t)r * FIVEL,
            ho, co, thought + (size_t)r * BB * LDIM);
        rh = ho; rc = co; tog ^= 1;
    }

    // ---- thought projection for decoder attention (h-independent) ----
    gemm_f32<<<dim3(HDIM / 64, RSTEPS * BB / 64), blk, 0, stream>>>(
        thought, nullptr, 0, dec_Wa2a, dec_ba2a, tproj, RSTEPS * BB, HDIM, LDIM, HDIM);

    // ---- decoder scan (starts again from h_enc/c_enc) ----
    float* dh = h_enc; float* dc = c_enc;
    tog = 0;
    const long ldout = (long)TDEC * VOUT;
    for (int t = 0; t < TDEC; ++t) {
        proj_h<<<gProj, blk, 0, stream>>>(dh, dec_Wh2a, dec_bh2a, hproj);
        attend<<<BB, blk, 0, stream>>>(tproj, hproj, thought, dec_Watt, attv, RSTEPS);
        float* ho = hbuf[2 + tog]; float* co = cbuf[2 + tog];
        lstm_step<<<gLstm, blk, 0, stream>>>(
            dec_pre + (size_t)t * BB * FIVEL, dh, dc, dec_Wh, dec_bh,
            attv, dec_Wa, dec_ba, ho, co, nullptr);
        gemm_f32<<<dim3((VOUT + 63) / 64, 1), blk, 0, stream>>>(
            ho, nullptr, 0, logit_W, logit_b, out + (size_t)t * VOUT, BB, VOUT, LDIM, ldout);
        log_softmax_<<<BB, blk, 0, stream>>>(out + (size_t)t * VOUT, ldout);
        dh = ho; dc = co; tog ^= 1;
    }
}

// Round 2
// 11575.603 us; speedup vs baseline: 1.6474x; 1.6474x over previous
//
#include <hip/hip_runtime.h>
#include <math.h>
#include <stdint.h>

#define BB     64
#define TENC   100
#define TDEC   50
#define LDIM   512
#define EE     512
#define HDIM   512
#define FIVEL  2560
#define RSTEPS 8
#define VOUT   30000

typedef __attribute__((ext_vector_type(8))) short short8v;   // 8 x bf16 (4 VGPR)
typedef __attribute__((ext_vector_type(4))) float floatx4;

__device__ __forceinline__ float sigmoidf_(float x) { return 1.0f / (1.0f + __expf(-x)); }
__device__ __forceinline__ unsigned short f2bf(float x) {
    unsigned u = __float_as_uint(x);
    u += 0x7FFFu + ((u >> 16) & 1u);           // round-to-nearest-even
    return (unsigned short)(u >> 16);
}
__device__ __forceinline__ float bf2f(unsigned short h) {
    return __uint_as_float(((unsigned)h) << 16);
}

// ---------------------------------------------------------------------------
// Gather embedding rows -> bf16 matrix X[m][E], m = t*BB + b.
// ---------------------------------------------------------------------------
__global__ __launch_bounds__(128)
void gather_embed(const float* __restrict__ embed, const int* __restrict__ tok,
                  int T, unsigned short* __restrict__ X)
{
    int m = blockIdx.x, t = m / BB, b = m % BB;
    const float* src = embed + (size_t)tok[b * T + t] * EE;
    float4 v = *(const float4*)(src + threadIdx.x * 4);
    ushort4 o = { f2bf(v.x), f2bf(v.y), f2bf(v.z), f2bf(v.w) };
    *(ushort4*)(X + (size_t)m * EE + threadIdx.x * 4) = o;
}

// ---------------------------------------------------------------------------
// WT[n][k] = bf16(W[k][n]).  W: [K][N] fp32.  grid (ceil(N/32), K/32), 256 thr.
// ---------------------------------------------------------------------------
__global__ __launch_bounds__(256)
void conv_transpose(const float* __restrict__ W, unsigned short* __restrict__ WT,
                    int K, int N)
{
    __shared__ float tile[32][33];
    int n0 = blockIdx.x * 32, k0 = blockIdx.y * 32;
    int tx = threadIdx.x & 31, ty = threadIdx.x >> 5;   // ty: 8 rows per pass
    #pragma unroll
    for (int i = 0; i < 4; ++i) {
        int k = k0 + ty + i * 8, n = n0 + tx;
        tile[ty + i * 8][tx] = (n < N) ? W[(size_t)k * N + n] : 0.f;
    }
    __syncthreads();
    #pragma unroll
    for (int i = 0; i < 4; ++i) {
        int n = n0 + ty + i * 8, k = k0 + tx;
        if (n < N) WT[(size_t)n * K + k] = f2bf(tile[tx][ty + i * 8]);
    }
}

// ---------------------------------------------------------------------------
// bf16 MFMA GEMM: C[m][n] = sum_k A[m][k] * BT[n][k] + bias[n]
// A: [M][K] bf16 (M = gridDim.y*128 exactly), BT: [N][K] bf16, K % 32 == 0.
// 128x128 tile, BK=32, 256 thr = 4 waves (2x2 of 64x64), 16x16x32 MFMA.
// LDS: linear [128][32] per operand, staged via global_load_lds(16B) with
// pre-swizzled source (chunk ^= (row>>1)&3); ds_read_b128 with same XOR.
// Output fp32 (C) or bf16 (Cb). remap: row m=(t*64+b) -> out row (b*TDEC+t).
// ---------------------------------------------------------------------------
__global__ __launch_bounds__(256)
void gemm_bf16(const unsigned short* __restrict__ A, const unsigned short* __restrict__ BT,
               const float* __restrict__ bias, float* __restrict__ C,
               unsigned short* __restrict__ Cb, int N, int K, long ldc, int remap)
{
    __shared__ unsigned short lds[2][128][32];   // 16 KiB
    const int tid  = threadIdx.x;
    const int wave = tid >> 6, lane = tid & 63;
    const int m0 = blockIdx.y * 128, n0 = blockIdx.x * 128;
    const int wr = wave >> 1, wc = wave & 1;     // 64x64 wave tile

    floatx4 acc[4][4] = {};

    const int sr  = lane >> 2;     // staging: row within 16-row group
    const int scp = lane & 3;      // staging: lds chunk (16B units)

    for (int k0 = 0; k0 < K; k0 += 32) {
        #pragma unroll
        for (int half = 0; half < 2; ++half) {
            int rbase = wave * 32 + half * 16;
            int r = rbase + sr;
            int c = scp ^ ((r >> 1) & 3);                    // pre-swizzled source
            const unsigned short* ga = A + (size_t)(m0 + r) * K + k0 + c * 8;
            int nr = n0 + r; if (nr >= N) nr = 0;            // clamp (stores guarded)
            const unsigned short* gb = BT + (size_t)nr * K + k0 + c * 8;
            __builtin_amdgcn_global_load_lds(
                (const __attribute__((address_space(1))) void*)ga,
                (__attribute__((address_space(3))) void*)&lds[0][rbase][0], 16, 0, 0);
            __builtin_amdgcn_global_load_lds(
                (const __attribute__((address_space(1))) void*)gb,
                (__attribute__((address_space(3))) void*)&lds[1][rbase][0], 16, 0, 0);
        }
        __syncthreads();

        short8v af[4], bv[4];
        #pragma unroll
        for (int i = 0; i < 4; ++i) {
            int ra = wr * 64 + i * 16 + (lane & 15);
            int ca = (lane >> 4) ^ ((ra >> 1) & 3);
            af[i] = *(const short8v*)&lds[0][ra][ca * 8];
            int rb = wc * 64 + i * 16 + (lane & 15);
            int cb = (lane >> 4) ^ ((rb >> 1) & 3);
            bv[i] = *(const short8v*)&lds[1][rb][cb * 8];
        }
        #pragma unroll
        for (int i = 0; i < 4; ++i)
            #pragma unroll
            for (int j = 0; j < 4; ++j)
                acc[i][j] = __builtin_amdgcn_mfma_f32_16x16x32_bf16(af[i], bv[j], acc[i][j], 0, 0, 0);
        __syncthreads();
    }

    // Epilogue: D row = (lane>>4)*4 + reg, col = lane&15  (m89-verified)
    const int crow0 = m0 + wr * 64 + (lane >> 4) * 4;
    const int ccol0 = n0 + wc * 64 + (lane & 15);
    #pragma unroll
    for (int i = 0; i < 4; ++i) {
        #pragma unroll
        for (int j = 0; j < 4; ++j) {
            int col = ccol0 + j * 16;
            if (col < N) {
                float bval = bias ? bias[col] : 0.f;
                #pragma unroll
                for (int rr = 0; rr < 4; ++rr) {
                    int m = crow0 + i * 16 + rr;
                    long orow = m;
                    if (remap) { int t = m >> 6, b = m & 63; orow = (long)b * TDEC + t; }
                    float v = acc[i][j][rr] + bval;
                    if (Cb) Cb[orow * ldc + col] = f2bf(v);
                    else    C [orow * ldc + col] = v;
                }
            }
        }
    }
}

// ---------------------------------------------------------------------------
// Small projection: out[b][n] = sum_k h[b][k]*W[k][n] + bias[n] (fp32, B=64)
// ---------------------------------------------------------------------------
__global__ __launch_bounds__(256)
void proj_h(const float* __restrict__ h, const float* __restrict__ W,
            const float* __restrict__ bias, float* __restrict__ out)
{
    __shared__ float hs[16][516];
    const int b0 = blockIdx.y * 16, n0 = blockIdx.x * 16;
    const int tid = threadIdx.x;
    {
        int r = tid >> 4, c4 = (tid & 15) * 4;
        #pragma unroll
        for (int j = 0; j < 8; ++j)
            *(float4*)&hs[r][c4 + 64 * j] = *(const float4*)&h[(b0 + r) * LDIM + c4 + 64 * j];
    }
    __syncthreads();
    const int bi = tid >> 4, ni = tid & 15;
    const int n = n0 + ni;
    float acc = 0.f;
    #pragma unroll 4
    for (int k = 0; k < LDIM; ++k) acc += hs[bi][k] * W[(long)k * HDIM + n];
    out[(b0 + bi) * HDIM + n] = acc + bias[n];
}

// ---------------------------------------------------------------------------
// Fused LSTM (maxout) step.  pre is bf16 (or null); optional att path.
// Writes h_out/c_out fp32; optional fp32 h_store and bf16 hb_store copies.
// ---------------------------------------------------------------------------
__global__ __launch_bounds__(256)
void lstm_step(const unsigned short* __restrict__ pre,
               const float* __restrict__ h_in, const float* __restrict__ c_in,
               const float* __restrict__ Wh, const float* __restrict__ bh,
               const float* __restrict__ att,
               const float* __restrict__ Wa, const float* __restrict__ ba,
               float* __restrict__ h_out, float* __restrict__ c_out,
               float* __restrict__ h_store, unsigned short* __restrict__ hb_store)
{
    __shared__ float hs[16][516];
    __shared__ float as_[16][516];
    const int b0 = blockIdx.y * 16, n0 = blockIdx.x * 16;
    const int tid = threadIdx.x;
    {
        int r = tid >> 4, c4 = (tid & 15) * 4;
        #pragma unroll
        for (int j = 0; j < 8; ++j)
            *(float4*)&hs[r][c4 + 64 * j] = *(const float4*)&h_in[(b0 + r) * LDIM + c4 + 64 * j];
        if (att) {
            #pragma unroll
            for (int j = 0; j < 8; ++j)
                *(float4*)&as_[r][c4 + 64 * j] = *(const float4*)&att[(b0 + r) * LDIM + c4 + 64 * j];
        }
    }
    __syncthreads();
    const int bi = tid >> 4, ni = tid & 15;
    const int b = b0 + bi, n = n0 + ni;

    float s[5];
    #pragma unroll
    for (int j = 0; j < 5; ++j) s[j] = bh[n + j * LDIM];
    if (ba) {
        #pragma unroll
        for (int j = 0; j < 5; ++j) s[j] += ba[n + j * LDIM];
    }
    if (pre) {
        #pragma unroll
        for (int j = 0; j < 5; ++j) s[j] += bf2f(pre[(long)b * FIVEL + n + j * LDIM]);
    }
    #pragma unroll 4
    for (int k = 0; k < LDIM; ++k) {
        float hk = hs[bi][k];
        const float* w = Wh + (long)k * FIVEL + n;
        #pragma unroll
        for (int j = 0; j < 5; ++j) s[j] += hk * w[j * LDIM];
    }
    if (att) {
        #pragma unroll 4
        for (int k = 0; k < LDIM; ++k) {
            float ak = as_[bi][k];
            const float* w = Wa + (long)k * FIVEL + n;
            #pragma unroll
            for (int j = 0; j < 5; ++j) s[j] += ak * w[j * LDIM];
        }
    }
    float ig = sigmoidf_(s[0]);
    float fg = sigmoidf_(s[1]);
    float og = sigmoidf_(s[2]);
    float tt = fmaxf(s[3], s[4]);
    float c2 = fg * c_in[(long)b * LDIM + n] + ig * tt;
    float h2 = og * tanhf(c2);
    h_out[(long)b * LDIM + n] = h2;
    c_out[(long)b * LDIM + n] = c2;
    if (h_store)  h_store[(long)b * LDIM + n] = h2;
    if (hb_store) hb_store[(long)b * LDIM + n] = f2bf(h2);
}

// ---------------------------------------------------------------------------
// Fused attention (unchanged from R1). proj/feats laid out [A][B][*].
// ---------------------------------------------------------------------------
__global__ __launch_bounds__(256)
void attend(const float* __restrict__ proj, const float* __restrict__ hproj,
            const float* __restrict__ feats, const float* __restrict__ Watt,
            float* __restrict__ att_v, int A)
{
    __shared__ float hp[512];
    __shared__ float wa[512];
    __shared__ float ealpha[128];
    const int b = blockIdx.x;
    const int tid = threadIdx.x;
    for (int i = tid; i < 512; i += 256) { hp[i] = hproj[b * HDIM + i]; wa[i] = Watt[i]; }
    __syncthreads();
    const int wave = tid >> 6, lane = tid & 63;
    for (int a = wave; a < A; a += 4) {
        const float* pr = proj + ((long)a * BB + b) * HDIM;
        float e = 0.f;
        #pragma unroll
        for (int j = 0; j < 8; ++j) {
            int hcol = lane + 64 * j;
            e += tanhf(pr[hcol] + hp[hcol]) * wa[hcol];
        }
        #pragma unroll
        for (int off = 32; off; off >>= 1) e += __shfl_xor(e, off);
        if (lane == 0) ealpha[a] = e;
    }
    __syncthreads();
    if (wave == 0) {
        float v1 = (lane < A) ? ealpha[lane] : -3.0e38f;
        float v2 = (lane + 64 < A) ? ealpha[lane + 64] : -3.0e38f;
        float m = fmaxf(v1, v2);
        #pragma unroll
        for (int off = 32; off; off >>= 1) m = fmaxf(m, __shfl_xor(m, off));
        float x1 = (lane < A) ? __expf(v1 - m) : 0.f;
        float x2 = (lane + 64 < A) ? __expf(v2 - m) : 0.f;
        float ssum = x1 + x2;
        #pragma unroll
        for (int off = 32; off; off >>= 1) ssum += __shfl_xor(ssum, off);
        float inv = 1.0f / ssum;
        if (lane < A) ealpha[lane] = x1 * inv;
        if (lane + 64 < A) ealpha[lane + 64] = x2 * inv;
    }
    __syncthreads();
    #pragma unroll
    for (int jj = 0; jj < 2; ++jj) {
        int l = tid + jj * 256;
        float acc = 0.f;
        for (int a = 0; a < A; ++a) acc += ealpha[a] * feats[((long)a * BB + b) * LDIM + l];
        att_v[(long)b * LDIM + l] = acc;
    }
}

// ---------------------------------------------------------------------------
// In-place log-softmax, one contiguous VOUT row per block (vectorized).
// ---------------------------------------------------------------------------
__global__ __launch_bounds__(256)
void log_softmax_(float* __restrict__ out)
{
    float* row = out + (size_t)blockIdx.x * VOUT;
    const int tid = threadIdx.x;
    float m = -3.0e38f, s = 0.f;
    for (int i = tid; i < VOUT / 4; i += 256) {
        float4 x = ((const float4*)row)[i];
        float xs[4] = {x.x, x.y, x.z, x.w};
        #pragma unroll
        for (int q = 0; q < 4; ++q) {
            float v = xs[q];
            if (v > m) { s = s * __expf(m - v) + 1.0f; m = v; }
            else       { s += __expf(v - m); }
        }
    }
    #pragma unroll
    for (int off = 32; off; off >>= 1) {
        float mo = __shfl_xor(m, off);
        float so = __shfl_xor(s, off);
        float mn = fmaxf(m, mo);
        s = s * __expf(m - mn) + so * __expf(mo - mn);
        m = mn;
    }
    __shared__ float ms[4], ss[4];
    const int wave = tid >> 6, lane = tid & 63;
    if (lane == 0) { ms[wave] = m; ss[wave] = s; }
    __syncthreads();
    float M2 = fmaxf(fmaxf(ms[0], ms[1]), fmaxf(ms[2], ms[3]));
    float S2 = ss[0] * __expf(ms[0] - M2) + ss[1] * __expf(ms[1] - M2) +
               ss[2] * __expf(ms[2] - M2) + ss[3] * __expf(ms[3] - M2);
    float lse = M2 + __logf(S2);
    for (int i = tid; i < VOUT / 4; i += 256) {
        float4 x = ((const float4*)row)[i];
        x.x -= lse; x.y -= lse; x.z -= lse; x.w -= lse;
        ((float4*)row)[i] = x;
    }
}

// ---------------------------------------------------------------------------
extern "C" void kernel_launch(void* const* d_in, const int* in_sizes, int n_in,
                              void* d_out_, int out_size, void* d_ws, size_t ws_size,
                              hipStream_t stream)
{
    const int*   code     = (const int*)  d_in[0];
    const int*   comment  = (const int*)  d_in[1];
    const float* embed    = (const float*)d_in[3];
    const float* enc_Wi   = (const float*)d_in[4];
    const float* enc_bi   = (const float*)d_in[5];
    const float* enc_Wh   = (const float*)d_in[6];
    const float* enc_bh   = (const float*)d_in[7];
    const float* rev_Wh   = (const float*)d_in[8];
    const float* rev_bh   = (const float*)d_in[9];
    const float* rev_Wa   = (const float*)d_in[10];
    const float* rev_ba   = (const float*)d_in[11];
    const float* rev_Wa2a = (const float*)d_in[12];
    const float* rev_ba2a = (const float*)d_in[13];
    const float* rev_Wh2a = (const float*)d_in[14];
    const float* rev_bh2a = (const float*)d_in[15];
    const float* rev_Watt = (const float*)d_in[16];
    const float* dec_Wi   = (const float*)d_in[18];
    const float* dec_bi   = (const float*)d_in[19];
    const float* dec_Wh   = (const float*)d_in[20];
    const float* dec_bh   = (const float*)d_in[21];
    const float* dec_Wa   = (const float*)d_in[22];
    const float* dec_ba   = (const float*)d_in[23];
    const float* dec_Wa2a = (const float*)d_in[24];
    const float* dec_ba2a = (const float*)d_in[25];
    const float* dec_Wh2a = (const float*)d_in[26];
    const float* dec_bh2a = (const float*)d_in[27];
    const float* dec_Watt = (const float*)d_in[28];
    const float* logit_W  = (const float*)d_in[30];
    const float* logit_b  = (const float*)d_in[31];
    float* out = (float*)d_out_;

    // ---- workspace carve-up (float units; all offsets 16B-aligned) ----
    float* ws = (float*)d_ws;
    size_t off = 0;
    // Region X: [0..8.19M)=enc_pre_b (prep+encoder); then rev_proj@0 (review)
    //           and logit_WT@3.2768M (post-review .. logit GEMM).
    const size_t XFL = 3276800 + 7680000;        // rev_proj + logit_WT
    float* Xp = ws + off; off += XFL;
    unsigned short* enc_pre_b = (unsigned short*)Xp;              // 6400*2560 bf16
    float*          rev_proj  = Xp;                               // 6400*512 f32
    unsigned short* logit_WT  = (unsigned short*)(Xp + 3276800);  // 30000*512 bf16

    unsigned short* dec_pre_b = (unsigned short*)(ws + off); off += 4096000;  // 3200*2560 bf16
    float* enc_hs    = ws + off; off += 3276800;                  // 6400*512 f32
    unsigned short* enc_hs_b = (unsigned short*)(ws + off); off += 1638400;   // bf16
    float* thought   = ws + off; off += 262144;                   // 8*64*512 f32
    unsigned short* thought_b = (unsigned short*)(ws + off); off += 131072;
    float* tproj     = ws + off; off += 262144;

    // Region Y: enc_x_b + dec_x_b (prep..pre-GEMMs); then dec_h_b (decode).
    float* Yp = ws + off; off += 2457600;
    unsigned short* enc_x_b = (unsigned short*)Yp;                 // 6400*512 bf16
    unsigned short* dec_x_b = (unsigned short*)(Yp + 1638400);     // 3200*512 bf16
    unsigned short* dec_h_b = (unsigned short*)Yp;                 // 3200*512 bf16 (aliases enc_x_b)

    unsigned short* WiT_enc = (unsigned short*)(ws + off); off += 655360;   // 2560*512 bf16
    unsigned short* WiT_dec = (unsigned short*)(ws + off); off += 655360;
    unsigned short* revWT   = (unsigned short*)(ws + off); off += 1048576;  // 8*512*512 bf16
    unsigned short* decWT   = (unsigned short*)(ws + off); off += 131072;   // 512*512 bf16

    float* hbuf[4]; float* cbuf[4];
    for (int i = 0; i < 4; ++i) { hbuf[i] = ws + off; off += (size_t)BB * LDIM; }
    for (int i = 0; i < 4; ++i) { cbuf[i] = ws + off; off += (size_t)BB * LDIM; }
    float* hproj = ws + off; off += (size_t)BB * HDIM;
    float* attv  = ws + off; off += (size_t)BB * LDIM;
    if (ws_size < off * sizeof(float)) return;

    const dim3 blk(256);
    const dim3 gLstm(LDIM / 16, BB / 16);
    const dim3 gProj(HDIM / 16, BB / 16);

    hipMemsetAsync(hbuf[0], 0, (size_t)BB * LDIM * sizeof(float), stream);
    hipMemsetAsync(cbuf[0], 0, (size_t)BB * LDIM * sizeof(float), stream);

    // ---- prep: gathers + weight transposes to bf16 [N][K] ----
    gather_embed<<<TENC * BB, 128, 0, stream>>>(embed, code, TENC, enc_x_b);
    gather_embed<<<TDEC * BB, 128, 0, stream>>>(embed, comment, TDEC, dec_x_b);
    conv_transpose<<<dim3(FIVEL / 32, EE / 32), blk, 0, stream>>>(enc_Wi, WiT_enc, EE, FIVEL);
    conv_transpose<<<dim3(FIVEL / 32, EE / 32), blk, 0, stream>>>(dec_Wi, WiT_dec, EE, FIVEL);
    for (int r = 0; r < RSTEPS; ++r)
        conv_transpose<<<dim3(16, 16), blk, 0, stream>>>(
            rev_Wa2a + (size_t)r * LDIM * HDIM, revWT + (size_t)r * LDIM * HDIM, LDIM, HDIM);
    conv_transpose<<<dim3(16, 16), blk, 0, stream>>>(dec_Wa2a, decWT, LDIM, HDIM);

    // ---- hoisted input GEMMs (bf16 MFMA, bf16 out) ----
    gemm_bf16<<<dim3(FIVEL / 128, TENC * BB / 128), blk, 0, stream>>>(
        enc_x_b, WiT_enc, enc_bi, nullptr, enc_pre_b, FIVEL, EE, FIVEL, 0);
    gemm_bf16<<<dim3(FIVEL / 128, TDEC * BB / 128), blk, 0, stream>>>(
        dec_x_b, WiT_dec, dec_bi, nullptr, dec_pre_b, FIVEL, EE, FIVEL, 0);

    // ---- encoder scan ----
    float *hc = hbuf[0], *cc = cbuf[0], *hn = hbuf[1], *cn = cbuf[1];
    for (int t = 0; t < TENC; ++t) {
        lstm_step<<<gLstm, blk, 0, stream>>>(
            enc_pre_b + (size_t)t * BB * FIVEL, hc, cc, enc_Wh, enc_bh,
            nullptr, nullptr, nullptr, hn, cn,
            enc_hs + (size_t)t * BB * LDIM, enc_hs_b + (size_t)t * BB * LDIM);
        float* tp;
        tp = hc; hc = hn; hn = tp;
        tp = cc; cc = cn; cn = tp;
    }
    float* h_enc = hc;   // hbuf[0] after 100 steps
    float* c_enc = cc;

    // logit_W transpose now (enc_pre_b region is dead past the encoder)
    conv_transpose<<<dim3((VOUT + 31) / 32, LDIM / 32), blk, 0, stream>>>(
        logit_W, logit_WT, LDIM, VOUT);

    // ---- review scan ----
    float* rh = h_enc; float* rc = c_enc;
    int tog = 0;
    for (int r = 0; r < RSTEPS; ++r) {
        gemm_bf16<<<dim3(HDIM / 128, TENC * BB / 128), blk, 0, stream>>>(
            enc_hs_b, revWT + (size_t)r * LDIM * HDIM, rev_ba2a + (size_t)r * HDIM,
            rev_proj, nullptr, HDIM, LDIM, HDIM, 0);
        proj_h<<<gProj, blk, 0, stream>>>(
            rh, rev_Wh2a + (size_t)r * LDIM * HDIM, rev_bh2a + (size_t)r * HDIM, hproj);
        attend<<<BB, blk, 0, stream>>>(rev_proj, hproj, enc_hs,
                                       rev_Watt + (size_t)r * HDIM, attv, TENC);
        float* ho = hbuf[2 + tog]; float* co = cbuf[2 + tog];
        lstm_step<<<gLstm, blk, 0, stream>>>(
            nullptr, rh, rc, rev_Wh + (size_t)r * LDIM * FIVEL, rev_bh + (size_t)r * FIVEL,
            attv, rev_Wa + (size_t)r * LDIM * FIVEL, rev_ba + (size_t)r * FIVEL,
            ho, co, thought + (size_t)r * BB * LDIM, thought_b + (size_t)r * BB * LDIM);
        rh = ho; rc = co; tog ^= 1;
    }

    // ---- thought projection for decoder attention ----
    gemm_bf16<<<dim3(HDIM / 128, RSTEPS * BB / 128), blk, 0, stream>>>(
        thought_b, decWT, dec_ba2a, tproj, nullptr, HDIM, LDIM, HDIM, 0);

    // ---- decoder scan (logits hoisted out) ----
    float* dh = h_enc; float* dc = c_enc;
    tog = 0;
    for (int t = 0; t < TDEC; ++t) {
        proj_h<<<gProj, blk, 0, stream>>>(dh, dec_Wh2a, dec_bh2a, hproj);
        attend<<<BB, blk, 0, stream>>>(tproj, hproj, thought, dec_Watt, attv, RSTEPS);
        float* ho = hbuf[2 + tog]; float* co = cbuf[2 + tog];
        lstm_step<<<gLstm, blk, 0, stream>>>(
            dec_pre_b + (size_t)t * BB * FIVEL, dh, dc, dec_Wh, dec_bh,
            attv, dec_Wa, dec_ba, ho, co, nullptr, dec_h_b + (size_t)t * BB * LDIM);
        dh = ho; dc = co; tog ^= 1;
    }

    // ---- one big logit GEMM (remapped rows) + log-softmax ----
    gemm_bf16<<<dim3((VOUT + 127) / 128, TDEC * BB / 128), blk, 0, stream>>>(
        dec_h_b, logit_WT, logit_b, out, nullptr, VOUT, LDIM, VOUT, 1);
    log_softmax_<<<TDEC * BB, blk, 0, stream>>>(out);
}

// Round 3
// 4012.361 us; speedup vs baseline: 4.7528x; 2.8850x over previous
//
#include <hip/hip_runtime.h>
#include <math.h>
#include <stdint.h>

#define BB     64
#define TENC   100
#define TDEC   50
#define LDIM   512
#define EE     512
#define HDIM   512
#define FIVEL  2560
#define RSTEPS 8
#define VOUT   30000

typedef __attribute__((ext_vector_type(8))) short short8v;   // 8 x bf16 (4 VGPR)
typedef __attribute__((ext_vector_type(4))) float floatx4;

__device__ __forceinline__ float sigmoidf_(float x) { return 1.0f / (1.0f + __expf(-x)); }
__device__ __forceinline__ unsigned short f2bf(float x) {
    unsigned u = __float_as_uint(x);
    u += 0x7FFFu + ((u >> 16) & 1u);           // round-to-nearest-even
    return (unsigned short)(u >> 16);
}
__device__ __forceinline__ float bf2f(unsigned short h) {
    return __uint_as_float(((unsigned)h) << 16);
}

// ---------------------------------------------------------------------------
// Gather embedding rows -> bf16 matrix X[m][E], m = t*BB + b.
// ---------------------------------------------------------------------------
__global__ __launch_bounds__(128)
void gather_embed(const float* __restrict__ embed, const int* __restrict__ tok,
                  int T, unsigned short* __restrict__ X)
{
    int m = blockIdx.x, t = m / BB, b = m % BB;
    const float* src = embed + (size_t)tok[b * T + t] * EE;
    float4 v = *(const float4*)(src + threadIdx.x * 4);
    ushort4 o = { f2bf(v.x), f2bf(v.y), f2bf(v.z), f2bf(v.w) };
    *(ushort4*)(X + (size_t)m * EE + threadIdx.x * 4) = o;
}

// ---------------------------------------------------------------------------
// WT[n][kofs+k] = bf16(W[k][n]).  W: [K][N] fp32.  grid (ceil(N/32), K/32).
// ---------------------------------------------------------------------------
__global__ __launch_bounds__(256)
void conv_transpose(const float* __restrict__ W, unsigned short* __restrict__ WT,
                    int K, int N, int ldWT, int kofs)
{
    __shared__ float tile[32][33];
    int n0 = blockIdx.x * 32, k0 = blockIdx.y * 32;
    int tx = threadIdx.x & 31, ty = threadIdx.x >> 5;
    #pragma unroll
    for (int i = 0; i < 4; ++i) {
        int k = k0 + ty + i * 8, n = n0 + tx;
        tile[ty + i * 8][tx] = (n < N) ? W[(size_t)k * N + n] : 0.f;
    }
    __syncthreads();
    #pragma unroll
    for (int i = 0; i < 4; ++i) {
        int n = n0 + ty + i * 8, k = k0 + tx;
        if (n < N) WT[(size_t)n * ldWT + kofs + k] = f2bf(tile[tx][ty + i * 8]);
    }
}

// ---------------------------------------------------------------------------
// bf16 MFMA GEMM (round-2-verified): C[m][n] = sum_k A[m][k]*BT[n][k] + bias[n]
// ---------------------------------------------------------------------------
__global__ __launch_bounds__(256)
void gemm_bf16(const unsigned short* __restrict__ A, const unsigned short* __restrict__ BT,
               const float* __restrict__ bias, float* __restrict__ C,
               unsigned short* __restrict__ Cb, int N, int K, long ldc, int remap)
{
    __shared__ unsigned short lds[2][128][32];
    const int tid  = threadIdx.x;
    const int wave = tid >> 6, lane = tid & 63;
    const int m0 = blockIdx.y * 128, n0 = blockIdx.x * 128;
    const int wr = wave >> 1, wc = wave & 1;

    floatx4 acc[4][4] = {};

    const int sr  = lane >> 2;
    const int scp = lane & 3;

    for (int k0 = 0; k0 < K; k0 += 32) {
        #pragma unroll
        for (int half = 0; half < 2; ++half) {
            int rbase = wave * 32 + half * 16;
            int r = rbase + sr;
            int c = scp ^ ((r >> 1) & 3);
            const unsigned short* ga = A + (size_t)(m0 + r) * K + k0 + c * 8;
            int nr = n0 + r; if (nr >= N) nr = 0;
            const unsigned short* gb = BT + (size_t)nr * K + k0 + c * 8;
            __builtin_amdgcn_global_load_lds(
                (const __attribute__((address_space(1))) void*)ga,
                (__attribute__((address_space(3))) void*)&lds[0][rbase][0], 16, 0, 0);
            __builtin_amdgcn_global_load_lds(
                (const __attribute__((address_space(1))) void*)gb,
                (__attribute__((address_space(3))) void*)&lds[1][rbase][0], 16, 0, 0);
        }
        __syncthreads();

        short8v af[4], bv[4];
        #pragma unroll
        for (int i = 0; i < 4; ++i) {
            int ra = wr * 64 + i * 16 + (lane & 15);
            int ca = (lane >> 4) ^ ((ra >> 1) & 3);
            af[i] = *(const short8v*)&lds[0][ra][ca * 8];
            int rb = wc * 64 + i * 16 + (lane & 15);
            int cb = (lane >> 4) ^ ((rb >> 1) & 3);
            bv[i] = *(const short8v*)&lds[1][rb][cb * 8];
        }
        #pragma unroll
        for (int i = 0; i < 4; ++i)
            #pragma unroll
            for (int j = 0; j < 4; ++j)
                acc[i][j] = __builtin_amdgcn_mfma_f32_16x16x32_bf16(af[i], bv[j], acc[i][j], 0, 0, 0);
        __syncthreads();
    }

    const int crow0 = m0 + wr * 64 + (lane >> 4) * 4;
    const int ccol0 = n0 + wc * 64 + (lane & 15);
    #pragma unroll
    for (int i = 0; i < 4; ++i) {
        #pragma unroll
        for (int j = 0; j < 4; ++j) {
            int col = ccol0 + j * 16;
            if (col < N) {
                float bval = bias ? bias[col] : 0.f;
                #pragma unroll
                for (int rr = 0; rr < 4; ++rr) {
                    int m = crow0 + i * 16 + rr;
                    long orow = m;
                    if (remap) { int t = m >> 6, b = m & 63; orow = (long)b * TDEC + t; }
                    float v = acc[i][j][rr] + bval;
                    if (Cb) Cb[orow * ldc + col] = f2bf(v);
                    else    C [orow * ldc + col] = v;
                }
            }
        }
    }
}

// ---------------------------------------------------------------------------
// Small-M (=64) MFMA GEMM over up to 3 concatenated bf16 A-segments (512 k
// each) against BT[n][ldBT] bf16.  Grid: 32 blocks x 256 thr; block covers a
// 16-col tile c0 and, for MODE 0, all 5 gate slices (B rows g*512 + c0 + i).
// MODE 0: fused maxout-LSTM epilogue. MODE 1 (NF=1): plain fp32 out + bias.
// ---------------------------------------------------------------------------
template<int NF, int MODE>
__global__ __launch_bounds__(256)
void smallgemm(const unsigned short* __restrict__ a0,
               const unsigned short* __restrict__ a1,
               const unsigned short* __restrict__ a2,
               const unsigned short* __restrict__ BT, int ldBT,
               const unsigned short* __restrict__ pre,
               const float* __restrict__ b0, const float* __restrict__ b1,
               const float* __restrict__ b2,
               const float* __restrict__ c_in, float* __restrict__ c_out,
               unsigned short* __restrict__ h_out, unsigned short* __restrict__ h_copy,
               float* __restrict__ f_out)
{
    __shared__ unsigned short Alds[64][128];        // 16 KB
    __shared__ unsigned short Blds[NF * 16][128];   // NF*4 KB
    const int tid = threadIdx.x;
    const int wave = tid >> 6, lane = tid & 63;
    const int c0 = blockIdx.x * 16;

    const unsigned short* segs[3] = {a0, a1, a2};
    const int nseg = a2 ? 3 : (a1 ? 2 : 1);
    const int NO = nseg * 4;                        // BK=128 tiles

    floatx4 acc[NF];
    #pragma unroll
    for (int g = 0; g < NF; ++g) acc[g] = (floatx4){0.f, 0.f, 0.f, 0.f};

    short8v ra[4], rb[NF];

    // A chunk: idx = tid + j*256 -> row idx>>4, chunk idx&15 (16B)
    // B chunk: idx = tid + j*256 (j<NF) -> LDS row idx>>4 -> global row
    //          (r>>4)*512 + c0 + (r&15)
    #define LOAD_TILE(ot_) do {                                                \
        int seg_ = (ot_) >> 2, k0_ = ((ot_) & 3) * 128;                        \
        const unsigned short* A_ = segs[seg_];                                 \
        _Pragma("unroll")                                                      \
        for (int j = 0; j < 4; ++j) {                                          \
            int idx = tid + j * 256; int r = idx >> 4, ch = idx & 15;          \
            ra[j] = *(const short8v*)(A_ + (size_t)r * 512 + k0_ + ch * 8);    \
        }                                                                      \
        _Pragma("unroll")                                                      \
        for (int j = 0; j < NF; ++j) {                                         \
            int idx = tid + j * 256; int r = idx >> 4, ch = idx & 15;          \
            int grow = (r >> 4) * 512 + c0 + (r & 15);                         \
            rb[j] = *(const short8v*)(BT + (size_t)grow * ldBT + seg_ * 512 + k0_ + ch * 8); \
        }                                                                      \
    } while (0)

    LOAD_TILE(0);
    for (int ot = 0; ot < NO; ++ot) {
        __syncthreads();
        #pragma unroll
        for (int j = 0; j < 4; ++j) {
            int idx = tid + j * 256; int r = idx >> 4, ch = idx & 15;
            *(short8v*)&Alds[r][(ch ^ (r & 7)) * 8] = ra[j];
        }
        #pragma unroll
        for (int j = 0; j < NF; ++j) {
            int idx = tid + j * 256; int r = idx >> 4, ch = idx & 15;
            *(short8v*)&Blds[r][(ch ^ (r & 7)) * 8] = rb[j];
        }
        __syncthreads();
        if (ot + 1 < NO) LOAD_TILE(ot + 1);   // prefetch overlaps MFMA below

        const int arow = wave * 16 + (lane & 15);
        const int q = lane >> 4;
        #pragma unroll
        for (int kk = 0; kk < 4; ++kk) {
            int ch = kk * 4 + q;
            short8v af = *(const short8v*)&Alds[arow][(ch ^ (arow & 7)) * 8];
            #pragma unroll
            for (int g = 0; g < NF; ++g) {
                int brow = g * 16 + (lane & 15);
                short8v bf = *(const short8v*)&Blds[brow][(ch ^ (brow & 7)) * 8];
                acc[g] = __builtin_amdgcn_mfma_f32_16x16x32_bf16(af, bf, acc[g], 0, 0, 0);
            }
        }
    }
    #undef LOAD_TILE

    // epilogue: M-row = wave*16 + (lane>>4)*4 + rr, col = c0 + (lane&15)
    const int m = wave * 16 + (lane >> 4) * 4;
    const int c = c0 + (lane & 15);
    if (MODE == 1) {
        float bv = b0 ? b0[c] : 0.f;
        #pragma unroll
        for (int rr = 0; rr < 4; ++rr)
            f_out[(size_t)(m + rr) * 512 + c] = acc[0][rr] + bv;
    } else {
        float bias[5];
        #pragma unroll
        for (int g = 0; g < 5; ++g) {
            float v = b0[g * 512 + c];
            if (b1) v += b1[g * 512 + c];
            if (b2) v += b2[g * 512 + c];
            bias[g] = v;
        }
        #pragma unroll
        for (int rr = 0; rr < 4; ++rr) {
            int row = m + rr;
            float s[5];
            #pragma unroll
            for (int g = 0; g < 5; ++g) {
                s[g] = acc[g][rr] + bias[g];
                if (pre) s[g] += bf2f(pre[(size_t)row * FIVEL + g * 512 + c]);
            }
            float ig = sigmoidf_(s[0]), fg = sigmoidf_(s[1]), og = sigmoidf_(s[2]);
            float tt = fmaxf(s[3], s[4]);
            float c2 = fg * c_in[(size_t)row * 512 + c] + ig * tt;
            float h2 = og * tanhf(c2);
            c_out[(size_t)row * 512 + c] = c2;
            unsigned short hb = f2bf(h2);
            h_out[(size_t)row * 512 + c] = hb;
            if (h_copy) h_copy[(size_t)row * 512 + c] = hb;
        }
    }
}

// ---------------------------------------------------------------------------
// Fused attention. proj (bf16 [A][64][512]), hproj (fp32 [64][512]),
// feats (bf16 [A][64][512]), attv out bf16 [64][512]. One block per b.
// ---------------------------------------------------------------------------
__global__ __launch_bounds__(256)
void attend(const unsigned short* __restrict__ proj, const float* __restrict__ hproj,
            const unsigned short* __restrict__ feats, const float* __restrict__ Watt,
            unsigned short* __restrict__ att_v, int A)
{
    __shared__ float hp[512];
    __shared__ float wa[512];
    __shared__ float ealpha[128];
    const int b = blockIdx.x;
    const int tid = threadIdx.x;
    for (int i = tid; i < 512; i += 256) { hp[i] = hproj[b * HDIM + i]; wa[i] = Watt[i]; }
    __syncthreads();
    const int wave = tid >> 6, lane = tid & 63;
    for (int a = wave; a < A; a += 4) {
        short8v pv = *(const short8v*)(proj + ((size_t)a * BB + b) * HDIM + lane * 8);
        float e = 0.f;
        #pragma unroll
        for (int j = 0; j < 8; ++j) {
            int hcol = lane * 8 + j;
            e += tanhf(bf2f((unsigned short)pv[j]) + hp[hcol]) * wa[hcol];
        }
        #pragma unroll
        for (int off = 32; off; off >>= 1) e += __shfl_xor(e, off);
        if (lane == 0) ealpha[a] = e;
    }
    __syncthreads();
    if (wave == 0) {
        float v1 = (lane < A) ? ealpha[lane] : -3.0e38f;
        float v2 = (lane + 64 < A) ? ealpha[lane + 64] : -3.0e38f;
        float m = fmaxf(v1, v2);
        #pragma unroll
        for (int off = 32; off; off >>= 1) m = fmaxf(m, __shfl_xor(m, off));
        float x1 = (lane < A) ? __expf(v1 - m) : 0.f;
        float x2 = (lane + 64 < A) ? __expf(v2 - m) : 0.f;
        float ssum = x1 + x2;
        #pragma unroll
        for (int off = 32; off; off >>= 1) ssum += __shfl_xor(ssum, off);
        float inv = 1.0f / ssum;
        if (lane < A) ealpha[lane] = x1 * inv;
        if (lane + 64 < A) ealpha[lane + 64] = x2 * inv;
    }
    __syncthreads();
    #pragma unroll
    for (int jj = 0; jj < 2; ++jj) {
        int l = tid + jj * 256;
        float acc = 0.f;
        for (int a = 0; a < A; ++a)
            acc += ealpha[a] * bf2f(feats[((size_t)a * BB + b) * LDIM + l]);
        att_v[(size_t)b * LDIM + l] = f2bf(acc);
    }
}

// ---------------------------------------------------------------------------
// In-place log-softmax, one contiguous VOUT row per block.
// ---------------------------------------------------------------------------
__global__ __launch_bounds__(256)
void log_softmax_(float* __restrict__ out)
{
    float* row = out + (size_t)blockIdx.x * VOUT;
    const int tid = threadIdx.x;
    float m = -3.0e38f, s = 0.f;
    for (int i = tid; i < VOUT / 4; i += 256) {
        float4 x = ((const float4*)row)[i];
        float xs[4] = {x.x, x.y, x.z, x.w};
        #pragma unroll
        for (int q = 0; q < 4; ++q) {
            float v = xs[q];
            if (v > m) { s = s * __expf(m - v) + 1.0f; m = v; }
            else       { s += __expf(v - m); }
        }
    }
    #pragma unroll
    for (int off = 32; off; off >>= 1) {
        float mo = __shfl_xor(m, off);
        float so = __shfl_xor(s, off);
        float mn = fmaxf(m, mo);
        s = s * __expf(m - mn) + so * __expf(mo - mn);
        m = mn;
    }
    __shared__ float ms[4], ss[4];
    const int wave = tid >> 6, lane = tid & 63;
    if (lane == 0) { ms[wave] = m; ss[wave] = s; }
    __syncthreads();
    float M2 = fmaxf(fmaxf(ms[0], ms[1]), fmaxf(ms[2], ms[3]));
    float S2 = ss[0] * __expf(ms[0] - M2) + ss[1] * __expf(ms[1] - M2) +
               ss[2] * __expf(ms[2] - M2) + ss[3] * __expf(ms[3] - M2);
    float lse = M2 + __logf(S2);
    for (int i = tid; i < VOUT / 4; i += 256) {
        float4 x = ((const float4*)row)[i];
        x.x -= lse; x.y -= lse; x.z -= lse; x.w -= lse;
        ((float4*)row)[i] = x;
    }
}

// ---------------------------------------------------------------------------
extern "C" void kernel_launch(void* const* d_in, const int* in_sizes, int n_in,
                              void* d_out_, int out_size, void* d_ws, size_t ws_size,
                              hipStream_t stream)
{
    const int*   code     = (const int*)  d_in[0];
    const int*   comment  = (const int*)  d_in[1];
    const float* embed    = (const float*)d_in[3];
    const float* enc_Wi   = (const float*)d_in[4];
    const float* enc_bi   = (const float*)d_in[5];
    const float* enc_Wh   = (const float*)d_in[6];
    const float* enc_bh   = (const float*)d_in[7];
    const float* rev_Wh   = (const float*)d_in[8];
    const float* rev_bh   = (const float*)d_in[9];
    const float* rev_Wa   = (const float*)d_in[10];
    const float* rev_ba   = (const float*)d_in[11];
    const float* rev_Wa2a = (const float*)d_in[12];
    const float* rev_ba2a = (const float*)d_in[13];
    const float* rev_Wh2a = (const float*)d_in[14];
    const float* rev_bh2a = (const float*)d_in[15];
    const float* rev_Watt = (const float*)d_in[16];
    const float* dec_Wi   = (const float*)d_in[18];
    const float* dec_bi   = (const float*)d_in[19];
    const float* dec_Wh   = (const float*)d_in[20];
    const float* dec_bh   = (const float*)d_in[21];
    const float* dec_Wa   = (const float*)d_in[22];
    const float* dec_ba   = (const float*)d_in[23];
    const float* dec_Wa2a = (const float*)d_in[24];
    const float* dec_ba2a = (const float*)d_in[25];
    const float* dec_Wh2a = (const float*)d_in[26];
    const float* dec_bh2a = (const float*)d_in[27];
    const float* dec_Watt = (const float*)d_in[28];
    const float* logit_W  = (const float*)d_in[30];
    const float* logit_b  = (const float*)d_in[31];
    float* out = (float*)d_out_;

    // ---- workspace carve-up (float units, total ~115.6 MB) ----
    float* ws = (float*)d_ws;
    size_t off = 0;

    // Region X: enc_pre_b (prep->encoder) then logit_WT (post-encoder->logit)
    float* X = ws; off += 8192000;                 // 6400*2560 bf16 = 8.192M fl
    unsigned short* enc_pre_b = (unsigned short*)X;
    unsigned short* logit_WT  = (unsigned short*)X;   // 30000*512 bf16 = 7.68M fl

    // Region U: prep {WiT_enc, enc_x_b} / review {rev_proj_b} / decode {dec_h_b}
    float* U = ws + off; off += 2293760;
    unsigned short* WiT_enc    = (unsigned short*)U;              // 2560*512 bf16
    unsigned short* enc_x_b    = (unsigned short*)(U + 655360);   // 6400*512 bf16
    unsigned short* rev_proj_b = (unsigned short*)U;              // 6400*512 bf16
    unsigned short* dec_h_b    = (unsigned short*)U;              // 3200*512 bf16

    unsigned short* enc_hs_b = (unsigned short*)(ws + off); off += 1638400;  // 6400*512
    unsigned short* encWhT   = (unsigned short*)(ws + off); off += 655360;   // 2560*512
    unsigned short* revWcomb = (unsigned short*)(ws + off); off += 10485760; // 8*2560*1024
    unsigned short* decWcomb = (unsigned short*)(ws + off); off += 1966080;  // 2560*1536
    unsigned short* revWT    = (unsigned short*)(ws + off); off += 1048576;  // 8*512*512
    unsigned short* decWT    = (unsigned short*)(ws + off); off += 131072;
    unsigned short* revWh2aT = (unsigned short*)(ws + off); off += 1048576;
    unsigned short* decWh2aT = (unsigned short*)(ws + off); off += 131072;
    unsigned short* dec_x_b  = (unsigned short*)(ws + off); off += 819200;   // 3200*512
    unsigned short* thought_b= (unsigned short*)(ws + off); off += 131072;   // 512*512
    unsigned short* tproj_b  = (unsigned short*)(ws + off); off += 131072;
    unsigned short* h0_b     = (unsigned short*)(ws + off); off += 16384;    // 64*512
    unsigned short* hb0      = (unsigned short*)(ws + off); off += 16384;
    unsigned short* hb1      = (unsigned short*)(ws + off); off += 16384;
    unsigned short* attv_b   = (unsigned short*)(ws + off); off += 16384;
    float* cbuf[4];
    for (int i = 0; i < 4; ++i) { cbuf[i] = ws + off; off += 32768; }
    float* hproj = ws + off; off += 32768;
    if (ws_size < off * sizeof(float)) return;

    unsigned short* hb[2] = {hb0, hb1};
    const dim3 blk(256);

    hipMemsetAsync(cbuf[0], 0, (size_t)BB * LDIM * sizeof(float), stream);
    hipMemsetAsync(h0_b, 0, (size_t)BB * LDIM * sizeof(unsigned short), stream);

    // ---- prep: gathers + all weight transposes (fp32 -> bf16 [N][K]) ----
    gather_embed<<<TENC * BB, 128, 0, stream>>>(embed, code, TENC, enc_x_b);
    gather_embed<<<TDEC * BB, 128, 0, stream>>>(embed, comment, TDEC, dec_x_b);
    conv_transpose<<<dim3(80, 16), blk, 0, stream>>>(enc_Wi, WiT_enc, 512, FIVEL, 512, 0);
    conv_transpose<<<dim3(80, 16), blk, 0, stream>>>(enc_Wh, encWhT, 512, FIVEL, 512, 0);
    for (int r = 0; r < RSTEPS; ++r) {
        conv_transpose<<<dim3(80, 16), blk, 0, stream>>>(
            rev_Wh + (size_t)r * 1310720, revWcomb + (size_t)r * 2621440, 512, FIVEL, 1024, 0);
        conv_transpose<<<dim3(80, 16), blk, 0, stream>>>(
            rev_Wa + (size_t)r * 1310720, revWcomb + (size_t)r * 2621440, 512, FIVEL, 1024, 512);
        conv_transpose<<<dim3(16, 16), blk, 0, stream>>>(
            rev_Wa2a + (size_t)r * 262144, revWT + (size_t)r * 262144, 512, 512, 512, 0);
        conv_transpose<<<dim3(16, 16), blk, 0, stream>>>(
            rev_Wh2a + (size_t)r * 262144, revWh2aT + (size_t)r * 262144, 512, 512, 512, 0);
    }
    conv_transpose<<<dim3(80, 16), blk, 0, stream>>>(dec_Wi, decWcomb, 512, FIVEL, 1536, 0);
    conv_transpose<<<dim3(80, 16), blk, 0, stream>>>(dec_Wh, decWcomb, 512, FIVEL, 1536, 512);
    conv_transpose<<<dim3(80, 16), blk, 0, stream>>>(dec_Wa, decWcomb, 512, FIVEL, 1536, 1024);
    conv_transpose<<<dim3(16, 16), blk, 0, stream>>>(dec_Wa2a, decWT, 512, 512, 512, 0);
    conv_transpose<<<dim3(16, 16), blk, 0, stream>>>(dec_Wh2a, decWh2aT, 512, 512, 512, 0);

    // ---- hoisted encoder input GEMM ----
    gemm_bf16<<<dim3(FIVEL / 128, TENC * BB / 128), blk, 0, stream>>>(
        enc_x_b, WiT_enc, enc_bi, nullptr, enc_pre_b, FIVEL, EE, FIVEL, 0);

    // ---- encoder scan (h carried bf16 directly in enc_hs_b slots) ----
    for (int t = 0; t < TENC; ++t) {
        const unsigned short* hin = (t == 0) ? h0_b : enc_hs_b + (size_t)(t - 1) * 32768;
        smallgemm<5, 0><<<32, blk, 0, stream>>>(
            hin, nullptr, nullptr, encWhT, 512,
            enc_pre_b + (size_t)t * BB * FIVEL,
            enc_bh, nullptr, nullptr,
            cbuf[t & 1], cbuf[(t + 1) & 1],
            enc_hs_b + (size_t)t * 32768, nullptr, nullptr);
    }
    const unsigned short* h_enc = enc_hs_b + (size_t)(TENC - 1) * 32768;
    // final c_enc lives in cbuf[0] (TENC even)

    // logit_W transpose (enc_pre_b region is dead now)
    conv_transpose<<<dim3((VOUT + 31) / 32, 16), blk, 0, stream>>>(
        logit_W, logit_WT, 512, VOUT, 512, 0);

    // ---- review scan ----
    const unsigned short* rh = h_enc;
    for (int r = 0; r < RSTEPS; ++r) {
        gemm_bf16<<<dim3(4, 50), blk, 0, stream>>>(
            enc_hs_b, revWT + (size_t)r * 262144, rev_ba2a + (size_t)r * HDIM,
            nullptr, rev_proj_b, HDIM, LDIM, HDIM, 0);
        smallgemm<1, 1><<<32, blk, 0, stream>>>(
            rh, nullptr, nullptr, revWh2aT + (size_t)r * 262144, 512,
            nullptr, rev_bh2a + (size_t)r * HDIM, nullptr, nullptr,
            nullptr, nullptr, nullptr, nullptr, hproj);
        attend<<<BB, blk, 0, stream>>>(rev_proj_b, hproj, enc_hs_b,
                                       rev_Watt + (size_t)r * HDIM, attv_b, TENC);
        const float* ci = (r == 0) ? cbuf[0] : cbuf[2 + ((r - 1) & 1)];
        smallgemm<5, 0><<<32, blk, 0, stream>>>(
            rh, attv_b, nullptr, revWcomb + (size_t)r * 2621440, 1024,
            nullptr, rev_bh + (size_t)r * FIVEL, rev_ba + (size_t)r * FIVEL, nullptr,
            ci, cbuf[2 + (r & 1)],
            hb[r & 1], thought_b + (size_t)r * 32768, nullptr);
        rh = hb[r & 1];
    }

    // ---- thought projection for decoder attention ----
    gemm_bf16<<<dim3(4, 4), blk, 0, stream>>>(
        thought_b, decWT, dec_ba2a, nullptr, tproj_b, HDIM, LDIM, HDIM, 0);

    // ---- decoder scan (x folded into step GEMM; logits hoisted) ----
    const unsigned short* dh = h_enc;
    for (int t = 0; t < TDEC; ++t) {
        smallgemm<1, 1><<<32, blk, 0, stream>>>(
            dh, nullptr, nullptr, decWh2aT, 512,
            nullptr, dec_bh2a, nullptr, nullptr,
            nullptr, nullptr, nullptr, nullptr, hproj);
        attend<<<BB, blk, 0, stream>>>(tproj_b, hproj, thought_b, dec_Watt, attv_b, RSTEPS);
        const float* ci = (t == 0) ? cbuf[0] : cbuf[2 + ((t - 1) & 1)];
        smallgemm<5, 0><<<32, blk, 0, stream>>>(
            dec_x_b + (size_t)t * 32768, dh, attv_b, decWcomb, 1536,
            nullptr, dec_bi, dec_bh, dec_ba,
            ci, cbuf[2 + (t & 1)],
            hb[t & 1], dec_h_b + (size_t)t * 32768, nullptr);
        dh = hb[t & 1];
    }

    // ---- one big logit GEMM (remapped rows) + log-softmax ----
    gemm_bf16<<<dim3((VOUT + 127) / 128, TDEC * BB / 128), blk, 0, stream>>>(
        dec_h_b, logit_WT, logit_b, out, nullptr, VOUT, LDIM, VOUT, 1);
    log_softmax_<<<TDEC * BB, blk, 0, stream>>>(out);
}